// Round 5
// baseline (178.505 us; speedup 1.0000x reference)
//
#include <hip/hip_runtime.h>

typedef float f32x4 __attribute__((ext_vector_type(4)));
typedef short short8 __attribute__((ext_vector_type(8)));
typedef unsigned short ushort_t;
typedef unsigned int uint_t;

// (B,T,D,H) = (64, 32, 256, 4); DIMS = [1024, 512, 256, 128, 64, 4]
constexpr int O_CAM   = 0;
constexpr int O_ROT   = 64;
constexpr int O_TRANS = 320;
constexpr int O_PLANE = 512;
constexpr int O_VALID = 66048;

// Workspace layout (byte offsets)
constexpr size_t B_G1   = 0;         // f32 [64][256]
constexpr size_t B_G2   = 65536;     // f32 [64][256]
constexpr size_t B_G    = 131072;    // f32 [4][64][512]
constexpr size_t B_ACC  = 655360;    // f32 [64][8]
constexpr size_t B_ABF  = 657408;    // bf16 [4][64][32][512]  (A' = A + G)
constexpr size_t B_CBF  = 9046016;   // bf16 [4][64][32][512]
constexpr size_t B_BT1  = 17434624;  // bf16 frag [4][16ks][16nt][64][8]
constexpr size_t B_BT2  = 18483200;  // bf16 frag [4][8][8][64][8]
constexpr size_t B_BT3  = 18745344;  // bf16 frag [4][4][4][64][8]
constexpr size_t B_BT0  = 18810880;  // bf16 frag [8hc][8ks][32nt][64][8]  (W0 a|c)
constexpr size_t B_BT0G = 20908032;  // bf16 frag [4h][16ks][32nt][64][8]  (W0 g1|g2)
// end = 23005184 bytes (~23 MB)

__device__ __forceinline__ ushort_t f2bf(float f) {
    uint_t u = __float_as_uint(f);
    return (ushort_t)((u + 0x7FFFu + ((u >> 16) & 1u)) >> 16);
}

__device__ __forceinline__ uint_t bfadd2_relu(uint_t a, uint_t c) {
    float lo = __uint_as_float(a << 16) + __uint_as_float(c << 16);
    float hi = __uint_as_float(a & 0xffff0000u) + __uint_as_float(c & 0xffff0000u);
    lo = fmaxf(lo, 0.f);
    hi = fmaxf(hi, 0.f);
    return (uint_t)f2bf(lo) | ((uint_t)f2bf(hi) << 16);
}

// ================= K-prep: weight reshuffles + group means + acc zero =================
__global__ __launch_bounds__(64) void k_prep(
    const float* __restrict__ emb, const int* __restrict__ np_,
    const float* __restrict__ w0, const float* __restrict__ w1,
    const float* __restrict__ w2, const float* __restrict__ w3,
    ushort_t* __restrict__ bt1, ushort_t* __restrict__ bt2, ushort_t* __restrict__ bt3,
    ushort_t* __restrict__ bt0, ushort_t* __restrict__ bt0g,
    float* __restrict__ g1, float* __restrict__ g2, float* __restrict__ accz)
{
    const int l = threadIdx.x;
    int c = blockIdx.x;
    if (c < 1344) {
        const float* w; ushort_t* dst; int K, N;
        if (c < 1024)      {           w = w1; dst = bt1 + (size_t)c*512; K = 512; N = 256; }
        else if (c < 1280) { c -= 1024; w = w2; dst = bt2 + (size_t)c*512; K = 256; N = 128; }
        else               { c -= 1280; w = w3; dst = bt3 + (size_t)c*512; K = 128; N = 64;  }
        const int NT = N/16, KS_NT = (K/32)*NT;
        const int h = c / KS_NT, rem = c % KS_NT, ks = rem / NT, nt = rem % NT;
        const int n = nt*16 + (l & 15);
        const int d0 = ks*32 + ((l >> 4) << 3);
        short8 o;
        #pragma unroll
        for (int j = 0; j < 8; ++j)
            o[j] = (short)f2bf(w[((size_t)(h*K + d0 + j))*N + n]);
        *(short8*)(dst + (size_t)l*8) = o;
    } else if (c < 3392) {
        c -= 1344;
        const int nt = c & 31, ks = (c >> 5) & 7, hc = c >> 8;
        const int h = hc >> 1, isC = hc & 1;
        const int n = nt*16 + (l & 15);
        const int d0 = isC*256 + ks*32 + ((l >> 4) << 3);
        short8 o;
        #pragma unroll
        for (int j = 0; j < 8; ++j)
            o[j] = (short)f2bf(w0[((size_t)h*1024 + d0 + j)*512 + n]);
        *(short8*)(bt0 + ((size_t)c*64 + l)*8) = o;
    } else if (c < 5440) {
        c -= 3392;
        const int h = c >> 9, ks = (c >> 5) & 15, nt = c & 31;
        const int n = nt*16 + (l & 15);
        const int d0 = 512 + ks*32 + ((l >> 4) << 3);
        short8 o;
        #pragma unroll
        for (int j = 0; j < 8; ++j)
            o[j] = (short)f2bf(w0[((size_t)h*1024 + d0 + j)*512 + n]);
        *(short8*)(bt0g + ((size_t)c*64 + l)*8) = o;
    } else if (c < 5504) {
        const int b = c - 5440;
        const int n0 = np_[2*b], n1 = np_[2*b+1];
        const float* e = emb + (size_t)b*8192;
        #pragma unroll
        for (int dd = 0; dd < 4; ++dd) {
            const int d = l + 64*dd;
            float a1 = 0.f, a2 = 0.f;
            for (int t = 0; t < 32; ++t) {
                float v = e[t*256 + d];
                if (t < n0) a1 += v;
                else if (t < n0 + n1) a2 += v;
            }
            g1[b*256 + d] = a1 / n0;
            g2[b*256 + d] = a2 / n1;
        }
    } else {
        #pragma unroll
        for (int i = 0; i < 8; ++i) accz[l*8 + i] = 0.f;
    }
}

// ================= K-Gm: G = (g1|g2) @ W0g + b0 via MFMA =================
__global__ __launch_bounds__(256) void k_Gm(
    const float* __restrict__ g1, const float* __restrict__ g2,
    const ushort_t* __restrict__ bt0g, const float* __restrict__ b0,
    float* __restrict__ G)
{
    const int h = blockIdx.x >> 1, nh = blockIdx.x & 1;
    const int tid = threadIdx.x;
    const int l = tid & 63, w = tid >> 6;
    const int lrow = l & 15, lko = l >> 4;

    __shared__ __align__(16) char xg[65536];   // bf16 [64][512], stride 1024B, swizzled

    for (int i = 0; i < 16; ++i) {
        const int flat = i*256 + tid;
        const int row = flat >> 6, ko = flat & 63;
        const int k = ko*8;
        const float* src = (k < 256) ? (g1 + row*256 + k) : (g2 + row*256 + (k - 256));
        const float4 v0 = *(const float4*)(src);
        const float4 v1 = *(const float4*)(src + 4);
        uint4 p;
        p.x = (uint_t)f2bf(v0.x) | ((uint_t)f2bf(v0.y) << 16);
        p.y = (uint_t)f2bf(v0.z) | ((uint_t)f2bf(v0.w) << 16);
        p.z = (uint_t)f2bf(v1.x) | ((uint_t)f2bf(v1.y) << 16);
        p.w = (uint_t)f2bf(v1.z) | ((uint_t)f2bf(v1.w) << 16);
        *(uint4*)(xg + ((row*1024 + ko*16) ^ ((row & 7) << 4))) = p;
    }
    __syncthreads();

    f32x4 acc[4][4];
    #pragma unroll
    for (int mt = 0; mt < 4; ++mt)
        #pragma unroll
        for (int nt = 0; nt < 4; ++nt) acc[mt][nt] = (f32x4){0.f,0.f,0.f,0.f};

    const ushort_t* bp = bt0g + (size_t)h*(16*32*512) + (size_t)(nh*16 + w*4)*512 + (size_t)l*8;
    short8 bb[2][4];
    #pragma unroll
    for (int nt = 0; nt < 4; ++nt) bb[0][nt] = *(const short8*)(bp + (size_t)nt*512);
    #pragma unroll
    for (int ks = 0; ks < 16; ++ks) {
        if (ks < 15) {
            #pragma unroll
            for (int nt = 0; nt < 4; ++nt)
                bb[(ks+1)&1][nt] = *(const short8*)(bp + (size_t)(ks+1)*16384 + (size_t)nt*512);
        }
        short8 a[4];
        #pragma unroll
        for (int mt = 0; mt < 4; ++mt)
            a[mt] = *(const short8*)(xg + (((mt*16 + lrow)*1024 + ks*64 + lko*16) ^ ((lrow & 7) << 4)));
        #pragma unroll
        for (int nt = 0; nt < 4; ++nt)
            #pragma unroll
            for (int mt = 0; mt < 4; ++mt)
                acc[mt][nt] = __builtin_amdgcn_mfma_f32_16x16x32_bf16(a[mt], bb[ks&1][nt], acc[mt][nt], 0, 0, 0);
    }

    #pragma unroll
    for (int nt = 0; nt < 4; ++nt) {
        const int col = nh*256 + w*64 + nt*16 + lrow;
        const float bias = b0[h*512 + col];
        #pragma unroll
        for (int mt = 0; mt < 4; ++mt)
            #pragma unroll
            for (int r = 0; r < 4; ++r) {
                const int brow = mt*16 + lko*4 + r;
                G[((size_t)h*64 + brow)*512 + col] = acc[mt][nt][r] + bias;
            }
    }
}

// ================= K-AC: A' and C via MFMA (M=32, K=256, N=512) =================
__global__ __launch_bounds__(256) void k_AC(
    const float* __restrict__ emb, const ushort_t* __restrict__ bt0,
    const float* __restrict__ Gbuf,
    ushort_t* __restrict__ Abf, ushort_t* __restrict__ Cbf)
{
    const int b = blockIdx.x, hc = blockIdx.y;
    const int h = hc >> 1, isC = hc & 1;
    const int tid = threadIdx.x;
    const int l = tid & 63, w4 = tid >> 6;
    const int lrow = l & 15, lko = l >> 4;

    __shared__ __align__(16) char es[16384];   // bf16 [32][256], stride 512B, swizzled

    {
        const float* eb = emb + (size_t)b*8192;
        #pragma unroll
        for (int j = 0; j < 16; ++j) {
            const int flat = j*256 + tid;
            const int row = flat >> 7, cp = flat & 127;
            const float2 v = *(const float2*)(eb + row*256 + cp*2);
            const uint_t p = (uint_t)f2bf(v.x) | ((uint_t)f2bf(v.y) << 16);
            const int byte = (row*512 + cp*4) ^ ((row & 7) << 4);
            *(uint_t*)(es + byte) = p;
        }
    }
    __syncthreads();

    f32x4 acc[2][8];
    #pragma unroll
    for (int mt = 0; mt < 2; ++mt)
        #pragma unroll
        for (int nt = 0; nt < 8; ++nt) acc[mt][nt] = (f32x4){0.f,0.f,0.f,0.f};

    const ushort_t* bp = bt0 + (size_t)hc*131072 + (size_t)(w4*8)*512 + (size_t)l*8;
    short8 bb[2][8];
    #pragma unroll
    for (int nt = 0; nt < 8; ++nt) bb[0][nt] = *(const short8*)(bp + nt*512);
    #pragma unroll
    for (int ks = 0; ks < 8; ++ks) {
        if (ks < 7) {
            #pragma unroll
            for (int nt = 0; nt < 8; ++nt)
                bb[(ks+1)&1][nt] = *(const short8*)(bp + (size_t)(ks+1)*16384 + nt*512);
        }
        const int o = (lrow*512 + ks*64 + lko*16) ^ ((lrow & 7) << 4);
        const short8 a0 = *(const short8*)(es + o);
        const short8 a1 = *(const short8*)(es + o + 8192);
        #pragma unroll
        for (int nt = 0; nt < 8; ++nt) {
            acc[0][nt] = __builtin_amdgcn_mfma_f32_16x16x32_bf16(a0, bb[ks&1][nt], acc[0][nt], 0, 0, 0);
            acc[1][nt] = __builtin_amdgcn_mfma_f32_16x16x32_bf16(a1, bb[ks&1][nt], acc[1][nt], 0, 0, 0);
        }
    }

    ushort_t* dst = (isC ? Cbf : Abf) + (size_t)(h*64 + b)*32*512;
    const float* Gr = Gbuf + (size_t)(h*64 + b)*512;
    #pragma unroll
    for (int nt = 0; nt < 8; ++nt) {
        const int col = (w4*8 + nt)*16 + lrow;
        const float g = isC ? 0.f : Gr[col];
        #pragma unroll
        for (int mt = 0; mt < 2; ++mt)
            #pragma unroll
            for (int r = 0; r < 4; ++r) {
                const int row = mt*16 + lko*4 + r;
                dst[row*512 + col] = f2bf(acc[mt][nt][r] + g);
            }
    }
}

// ================= K-MLP: M=64 row-tile fused MLP =================
// grid 1792: x<1024: h=3, b=x>>4, t0=(x&15)*2   (rows = 2t x 32s)
//            x>=1024: y=x-1024, h=y>>8, b=(y>>2)&63, t0=(y&3)*4 (rows = 4t x 16s window)
// block 256 threads = 4 waves; wave w owns N-slice; M=64 = 4 MFMA tiles.
// LDS: [0,32768) X0/X1/X2 overlay; [16384,32768) X3 f32; [32768,33792) X4; [33792,34816) w4L
__global__ __launch_bounds__(256, 4) void k_mlp(
    const ushort_t* __restrict__ Abf, const ushort_t* __restrict__ Cbf,
    const ushort_t* __restrict__ bt1, const ushort_t* __restrict__ bt2, const ushort_t* __restrict__ bt3,
    const float* __restrict__ b1, const float* __restrict__ b2, const float* __restrict__ b3,
    const float* __restrict__ w4, const float* __restrict__ b4,
    const int* __restrict__ np_, float* __restrict__ out, float* __restrict__ accbuf)
{
    const int x = blockIdx.x;
    const bool isH3 = (x < 1024);
    int h, b, t0;
    int n0 = 0, n1 = 0;
    if (isH3) {
        h = 3; b = x >> 4; t0 = (x & 15) * 2;
    } else {
        const int y = x - 1024;
        h = y >> 8; b = (y >> 2) & 63; t0 = (y & 3) * 4;
        n0 = np_[2*b]; n1 = np_[2*b+1];
        if (t0 >= n0) return;
    }

    __shared__ __align__(16) char smem[34816];
    char* X  = smem;                       // X0/X1 [64][256] bf16 (32KB), X2 [64][128] bf16 (16KB)
    float* X3 = (float*)(smem + 16384);    // f32 [64][64]
    float* X4 = (float*)(smem + 32768);    // f32 [64][4]
    float* w4L = (float*)(smem + 33792);   // f32 [256]

    const int tid = threadIdx.x;
    const int l = tid & 63, w = tid >> 6;
    const int lrow = l & 15, lko = l >> 4;
    const size_t hb = (size_t)(h*64 + b);
    const uint4* Arows = (const uint4*)(Abf + hb*32*512);   // 64 uint4 per row
    const uint4* Crows = (const uint4*)(Cbf + hb*32*512);

    // preload biases + w4 into LDS
    float bias1v[4], bias2v[2], bias3v;
    #pragma unroll
    for (int nt = 0; nt < 4; ++nt) bias1v[nt] = b1[h*256 + w*64 + nt*16 + lrow];
    #pragma unroll
    for (int nt = 0; nt < 2; ++nt) bias2v[nt] = b2[h*128 + w*32 + nt*16 + lrow];
    bias3v = b3[h*64 + w*16 + lrow];
    w4L[tid] = w4[h*256 + tid];

    // ---- layer1: two K=256 half-passes over a single 32KB X0 buffer ----
    f32x4 acc1[4][4];
    #pragma unroll
    for (int mt = 0; mt < 4; ++mt)
        #pragma unroll
        for (int nt = 0; nt < 4; ++nt) acc1[mt][nt] = (f32x4){0.f,0.f,0.f,0.f};

    for (int p = 0; p < 2; ++p) {
        __syncthreads();   // previous pass readers done (p=0: w4L visible later anyway)
        // build X0 half: rows 0..63, cols p*256..p*256+255
        #pragma unroll
        for (int i = 0; i < 8; ++i) {
            const int flat = i*256 + tid;        // [64 rows][32 uint4]
            const int row = flat >> 5, q4 = flat & 31;
            int trow, crow;
            if (isH3) { trow = t0 + (row >> 5); crow = row & 31; }
            else      { trow = t0 + (row >> 4); crow = n0 + (row & 15); }
            const uint4 aa = Arows[(size_t)trow*64 + p*32 + q4];
            const uint4 cc = Crows[(size_t)crow*64 + p*32 + q4];
            uint4 v;
            v.x = bfadd2_relu(aa.x, cc.x);
            v.y = bfadd2_relu(aa.y, cc.y);
            v.z = bfadd2_relu(aa.z, cc.z);
            v.w = bfadd2_relu(aa.w, cc.w);
            *(uint4*)(X + ((row*512 + q4*16) ^ ((row & 7) << 4))) = v;
        }
        __syncthreads();

        const ushort_t* bp = bt1 + (size_t)((h*16 + p*8)*16 + w*4)*512 + (size_t)l*8;
        short8 bb[2][4];
        #pragma unroll
        for (int nt = 0; nt < 4; ++nt) bb[0][nt] = *(const short8*)(bp + (size_t)nt*512);
        #pragma unroll
        for (int ks = 0; ks < 8; ++ks) {
            if (ks < 7) {
                #pragma unroll
                for (int nt = 0; nt < 4; ++nt)
                    bb[(ks+1)&1][nt] = *(const short8*)(bp + (size_t)(ks+1)*8192 + (size_t)nt*512);
            }
            short8 a[4];
            #pragma unroll
            for (int mt = 0; mt < 4; ++mt)
                a[mt] = *(const short8*)(X + (((mt*16 + lrow)*512 + ks*64 + lko*16) ^ ((lrow & 7) << 4)));
            #pragma unroll
            for (int nt = 0; nt < 4; ++nt)
                #pragma unroll
                for (int mt = 0; mt < 4; ++mt)
                    acc1[mt][nt] = __builtin_amdgcn_mfma_f32_16x16x32_bf16(a[mt], bb[ks&1][nt], acc1[mt][nt], 0, 0, 0);
        }
    }
    __syncthreads();

    // X1 write (overlays X0)
    #pragma unroll
    for (int nt = 0; nt < 4; ++nt) {
        const int col = w*64 + nt*16 + lrow;
        #pragma unroll
        for (int mt = 0; mt < 4; ++mt)
            #pragma unroll
            for (int r = 0; r < 4; ++r) {
                const int row = mt*16 + lko*4 + r;
                *(ushort_t*)(X + ((row*512 + col*2) ^ ((row & 7) << 4))) =
                    f2bf(fmaxf(acc1[mt][nt][r] + bias1v[nt], 0.f));
            }
    }
    __syncthreads();

    // ---- layer2: K=256, N=128; wave owns 2 nt ----
    f32x4 acc2[4][2];
    #pragma unroll
    for (int mt = 0; mt < 4; ++mt)
        #pragma unroll
        for (int nt = 0; nt < 2; ++nt) acc2[mt][nt] = (f32x4){0.f,0.f,0.f,0.f};
    {
        const ushort_t* bp = bt2 + (size_t)(h*8*8 + w*2)*512 + (size_t)l*8;
        short8 bb[2][2];
        #pragma unroll
        for (int nt = 0; nt < 2; ++nt) bb[0][nt] = *(const short8*)(bp + (size_t)nt*512);
        #pragma unroll
        for (int ks = 0; ks < 8; ++ks) {
            if (ks < 7) {
                #pragma unroll
                for (int nt = 0; nt < 2; ++nt)
                    bb[(ks+1)&1][nt] = *(const short8*)(bp + (size_t)(ks+1)*4096 + (size_t)nt*512);
            }
            short8 a[4];
            #pragma unroll
            for (int mt = 0; mt < 4; ++mt)
                a[mt] = *(const short8*)(X + (((mt*16 + lrow)*512 + ks*64 + lko*16) ^ ((lrow & 7) << 4)));
            #pragma unroll
            for (int nt = 0; nt < 2; ++nt)
                #pragma unroll
                for (int mt = 0; mt < 4; ++mt)
                    acc2[mt][nt] = __builtin_amdgcn_mfma_f32_16x16x32_bf16(a[mt], bb[ks&1][nt], acc2[mt][nt], 0, 0, 0);
        }
    }
    __syncthreads();

    // X2 write (overlays X1), [64][128] bf16 stride 256B
    #pragma unroll
    for (int nt = 0; nt < 2; ++nt) {
        const int col = w*32 + nt*16 + lrow;
        #pragma unroll
        for (int mt = 0; mt < 4; ++mt)
            #pragma unroll
            for (int r = 0; r < 4; ++r) {
                const int row = mt*16 + lko*4 + r;
                *(ushort_t*)(X + ((row*256 + col*2) ^ ((row & 7) << 4))) =
                    f2bf(fmaxf(acc2[mt][nt][r] + bias2v[nt], 0.f));
            }
    }
    __syncthreads();

    // ---- layer3: K=128, N=64; wave owns nt=w ----
    f32x4 acc3[4];
    #pragma unroll
    for (int mt = 0; mt < 4; ++mt) acc3[mt] = (f32x4){0.f,0.f,0.f,0.f};
    {
        const ushort_t* bp = bt3 + (size_t)(h*4*4 + w)*512 + (size_t)l*8;
        short8 F3[4];
        #pragma unroll
        for (int ks = 0; ks < 4; ++ks) F3[ks] = *(const short8*)(bp + (size_t)ks*2048);
        #pragma unroll
        for (int ks = 0; ks < 4; ++ks) {
            short8 a[4];
            #pragma unroll
            for (int mt = 0; mt < 4; ++mt)
                a[mt] = *(const short8*)(X + (((mt*16 + lrow)*256 + ks*64 + lko*16) ^ ((lrow & 7) << 4)));
            #pragma unroll
            for (int mt = 0; mt < 4; ++mt)
                acc3[mt] = __builtin_amdgcn_mfma_f32_16x16x32_bf16(a[mt], F3[ks], acc3[mt], 0, 0, 0);
        }
    }
    // X3 write @16K (X1-upper dead); X2 @0..16K still being read by others -> disjoint, no bar
    {
        const int col = w*16 + lrow;
        #pragma unroll
        for (int mt = 0; mt < 4; ++mt)
            #pragma unroll
            for (int r = 0; r < 4; ++r)
                X3[(mt*16 + lko*4 + r)*64 + col] = fmaxf(acc3[mt][r] + bias3v, 0.f);
    }
    __syncthreads();

    // ---- layer4: 64 -> 4 (VALU, one output per thread, bank-staggered reads) ----
    {
        const int row = tid >> 2, o = tid & 3;
        float a = b4[h*4 + o];
        #pragma unroll
        for (int dd = 0; dd < 16; ++dd) {
            const int dbase = ((row + dd) & 15) * 4;
            const float4 xv = *(const float4*)(X3 + row*64 + dbase);
            a = fmaf(xv.x, w4L[(dbase + 0)*4 + o], a);
            a = fmaf(xv.y, w4L[(dbase + 1)*4 + o], a);
            a = fmaf(xv.z, w4L[(dbase + 2)*4 + o], a);
            a = fmaf(xv.w, w4L[(dbase + 3)*4 + o], a);
        }
        X4[row*4 + o] = a;
    }
    __syncthreads();

    // ---- outputs ----
    if (isH3) {
        if (tid < 64) {
            const int tq = tid >> 5, s = tid & 31;
            out[O_PLANE + b*1024 + (t0 + tq)*32 + s] = 1.f / (1.f + expf(-X4[tid*4]));
        }
    } else {
        const int nj = (h == 0) ? 1 : ((h == 1) ? 4 : 3);
        const int j = w;
        if (j < nj) {
            const int tq = l >> 4, sr = l & 15;
            const bool valid = ((t0 + tq) < n0) && (sr < n1);
            float v = valid ? X4[l*4 + j] : 0.f;
            #pragma unroll
            for (int off = 32; off > 0; off >>= 1) v += __shfl_down(v, off);
            if (l == 0) {
                const int slot = (h == 0) ? 0 : ((h == 1) ? 1 + j : 5 + j);
                atomicAdd(&accbuf[b*8 + slot], v);
            }
        }
    }
}

// ================= K-final: valid mask + finalize reductions =================
__global__ __launch_bounds__(1024) void k_final(
    const int* __restrict__ np_, const float* __restrict__ acc, float* __restrict__ out)
{
    const int b = blockIdx.x, tid = threadIdx.x;
    const int n0 = np_[2*b], n1 = np_[2*b+1];
    const int t = tid >> 5, s = tid & 31;
    out[O_VALID + b*1024 + tid] = (t < n0 && s >= n0 && s < n0 + n1) ? 1.f : 0.f;
    const float pf = (float)(n0 * n1);
    if (tid == 0) {
        out[O_CAM + b] = 1.f / (1.f + expf(-acc[b*8] / pf));
    } else if (tid <= 4) {
        out[O_ROT + b*4 + (tid - 1)] = acc[b*8 + tid] / pf;
    } else if (tid <= 7) {
        out[O_TRANS + b*3 + (tid - 5)] = acc[b*8 + tid] / pf;
    }
}

extern "C" void kernel_launch(void* const* d_in, const int* in_sizes, int n_in,
                              void* d_out, int out_size, void* d_ws, size_t ws_size,
                              hipStream_t stream) {
    (void)in_sizes; (void)n_in; (void)out_size; (void)ws_size;
    const float* emb = (const float*)d_in[0];
    const int*   np_ = (const int*)d_in[1];
    const float* w0  = (const float*)d_in[2];
    const float* b0  = (const float*)d_in[3];
    const float* w1  = (const float*)d_in[4];
    const float* b1  = (const float*)d_in[5];
    const float* w2  = (const float*)d_in[6];
    const float* b2  = (const float*)d_in[7];
    const float* w3  = (const float*)d_in[8];
    const float* b3  = (const float*)d_in[9];
    const float* w4  = (const float*)d_in[10];
    const float* b4  = (const float*)d_in[11];

    char* W = (char*)d_ws;
    float* out = (float*)d_out;
    float*    g1   = (float*)(W + B_G1);
    float*    g2   = (float*)(W + B_G2);
    float*    G    = (float*)(W + B_G);
    float*    acc  = (float*)(W + B_ACC);
    ushort_t* Abf  = (ushort_t*)(W + B_ABF);
    ushort_t* Cbf  = (ushort_t*)(W + B_CBF);
    ushort_t* bt1  = (ushort_t*)(W + B_BT1);
    ushort_t* bt2  = (ushort_t*)(W + B_BT2);
    ushort_t* bt3  = (ushort_t*)(W + B_BT3);
    ushort_t* bt0  = (ushort_t*)(W + B_BT0);
    ushort_t* bt0g = (ushort_t*)(W + B_BT0G);

    k_prep<<<5505, 64, 0, stream>>>(emb, np_, w0, w1, w2, w3,
                                    bt1, bt2, bt3, bt0, bt0g, g1, g2, acc);
    k_Gm<<<8, 256, 0, stream>>>(g1, g2, bt0g, b0, G);
    k_AC<<<dim3(64, 8), 256, 0, stream>>>(emb, bt0, G, Abf, Cbf);
    k_mlp<<<1792, 256, 0, stream>>>(Abf, Cbf, bt1, bt2, bt3,
                                    b1, b2, b3, w4, b4, np_, out, acc);
    k_final<<<64, 1024, 0, stream>>>(np_, acc, out);
}

// Round 6
// 129.937 us; speedup vs baseline: 1.3738x; 1.3738x over previous
//
#include <hip/hip_runtime.h>

typedef float f32x4 __attribute__((ext_vector_type(4)));
typedef short short8 __attribute__((ext_vector_type(8)));
typedef unsigned short ushort_t;
typedef unsigned int uint_t;

// (B,T,D,H) = (64, 32, 256, 4); DIMS = [1024, 512, 256, 128, 64, 4]
constexpr int O_CAM   = 0;
constexpr int O_ROT   = 64;
constexpr int O_TRANS = 320;
constexpr int O_PLANE = 512;
constexpr int O_VALID = 66048;

// Workspace layout (byte offsets)
constexpr size_t B_G1   = 0;         // f32 [64][256]
constexpr size_t B_G2   = 65536;     // f32 [64][256]
constexpr size_t B_ACC  = 131072;    // f32 [64][8]
constexpr size_t B_ABF  = 133120;    // bf16 [4][64][32][512]  (A' = emb@W0a + G + b0)
constexpr size_t B_CBF  = 8521728;   // bf16 [4][64][32][512]
constexpr size_t B_BT1  = 16910336;  // bf16 frag [4][16ks][16nt][64][8]
constexpr size_t B_BT2  = 17958912;  // bf16 frag [4][8][8][64][8]
constexpr size_t B_BT3  = 18221056;  // bf16 frag [4][4][4][64][8]
constexpr size_t B_BT0F = 18286592;  // bf16 frag [4h][32ks][32nt][64][8]  (full W0)
// end = 22480896 bytes (~22.5 MB)

__device__ __forceinline__ ushort_t f2bf(float f) {
    uint_t u = __float_as_uint(f);
    return (ushort_t)((u + 0x7FFFu + ((u >> 16) & 1u)) >> 16);
}

__device__ __forceinline__ uint_t bfadd2_relu(uint_t a, uint_t c) {
    float lo = __uint_as_float(a << 16) + __uint_as_float(c << 16);
    float hi = __uint_as_float(a & 0xffff0000u) + __uint_as_float(c & 0xffff0000u);
    lo = fmaxf(lo, 0.f);
    hi = fmaxf(hi, 0.f);
    return (uint_t)f2bf(lo) | ((uint_t)f2bf(hi) << 16);
}

// ================= K-prep: weight reshuffles + group means + acc zero + valid mask =================
// grid x: [0,1344) w1/w2/w3 frags | [1344,5440) full-W0 frags | [5440,5504) g means
//         5504 acc zero | [5505,5569) valid mask
__global__ __launch_bounds__(64) void k_prep(
    const float* __restrict__ emb, const int* __restrict__ np_,
    const float* __restrict__ w0, const float* __restrict__ w1,
    const float* __restrict__ w2, const float* __restrict__ w3,
    ushort_t* __restrict__ bt1, ushort_t* __restrict__ bt2, ushort_t* __restrict__ bt3,
    ushort_t* __restrict__ bt0f,
    float* __restrict__ g1, float* __restrict__ g2, float* __restrict__ accz,
    float* __restrict__ out)
{
    const int l = threadIdx.x;
    int c = blockIdx.x;
    if (c < 1344) {
        const float* w; ushort_t* dst; int K, N;
        if (c < 1024)      {           w = w1; dst = bt1 + (size_t)c*512; K = 512; N = 256; }
        else if (c < 1280) { c -= 1024; w = w2; dst = bt2 + (size_t)c*512; K = 256; N = 128; }
        else               { c -= 1280; w = w3; dst = bt3 + (size_t)c*512; K = 128; N = 64;  }
        const int NT = N/16, KS_NT = (K/32)*NT;
        const int h = c / KS_NT, rem = c % KS_NT, ks = rem / NT, nt = rem % NT;
        const int n = nt*16 + (l & 15);
        const int d0 = ks*32 + ((l >> 4) << 3);
        short8 o;
        #pragma unroll
        for (int j = 0; j < 8; ++j)
            o[j] = (short)f2bf(w[((size_t)(h*K + d0 + j))*N + n]);
        *(short8*)(dst + (size_t)l*8) = o;
    } else if (c < 5440) {
        const int c2 = c - 1344;                 // (h, ks, nt) over full W0
        const int h = c2 >> 10, ks = (c2 >> 5) & 31, nt = c2 & 31;
        const int n = nt*16 + (l & 15);
        const int d0 = ks*32 + ((l >> 4) << 3);
        short8 o;
        #pragma unroll
        for (int j = 0; j < 8; ++j)
            o[j] = (short)f2bf(w0[((size_t)h*1024 + d0 + j)*512 + n]);
        *(short8*)(bt0f + (size_t)c2*512 + (size_t)l*8) = o;
    } else if (c < 5504) {
        const int b = c - 5440;
        const int n0 = np_[2*b], n1 = np_[2*b+1];
        const float* e = emb + (size_t)b*8192;
        #pragma unroll
        for (int dd = 0; dd < 4; ++dd) {
            const int d = l + 64*dd;
            float a1 = 0.f, a2 = 0.f;
            for (int t = 0; t < 32; ++t) {
                float v = e[t*256 + d];
                if (t < n0) a1 += v;
                else if (t < n0 + n1) a2 += v;
            }
            g1[b*256 + d] = a1 / n0;
            g2[b*256 + d] = a2 / n1;
        }
    } else if (c == 5504) {
        #pragma unroll
        for (int i = 0; i < 8; ++i) accz[l*8 + i] = 0.f;
    } else {
        const int b = c - 5505;
        const int n0 = np_[2*b], n1 = np_[2*b+1];
        float* dst = out + O_VALID + b*1024;
        #pragma unroll
        for (int i = 0; i < 16; ++i) {
            const int j = l*16 + i;
            const int t = j >> 5, s = j & 31;
            dst[j] = (t < n0 && s >= n0 && s < n0 + n1) ? 1.f : 0.f;
        }
    }
}

// ================= K-AC: A' (with G+b0 folded) and C via MFMA =================
// grid (64 b, 8 hc); hc = h*2 + isC.
// A' = emb@W0[0:256] + g1@W0[512:768] + g2@W0[768:1024] + b0   (K = 768)
// C  = emb@W0[256:512]                                          (K = 256)
__global__ __launch_bounds__(256) void k_AC(
    const float* __restrict__ emb, const ushort_t* __restrict__ bt0f,
    const float* __restrict__ g1, const float* __restrict__ g2,
    const float* __restrict__ b0,
    ushort_t* __restrict__ Abf, ushort_t* __restrict__ Cbf)
{
    const int b = blockIdx.x, hc = blockIdx.y;
    const int h = hc >> 1, isC = hc & 1;
    const int tid = threadIdx.x;
    const int l = tid & 63, w4 = tid >> 6;
    const int lrow = l & 15, lko = l >> 4;

    __shared__ __align__(16) char es[16384];       // bf16 [32][256], stride 512B, swizzled
    __shared__ __align__(16) ushort_t gs[512];     // bf16 [g1|g2]

    {
        const float* eb = emb + (size_t)b*8192;
        #pragma unroll
        for (int j = 0; j < 16; ++j) {
            const int flat = j*256 + tid;
            const int row = flat >> 7, cp = flat & 127;
            const float2 v = *(const float2*)(eb + row*256 + cp*2);
            const uint_t p = (uint_t)f2bf(v.x) | ((uint_t)f2bf(v.y) << 16);
            const int byte = (row*512 + cp*4) ^ ((row & 7) << 4);
            *(uint_t*)(es + byte) = p;
        }
    }
    if (!isC && tid < 64) {
        const float* src = (tid < 32) ? (g1 + b*256 + tid*8) : (g2 + b*256 + (tid - 32)*8);
        const float4 v0 = *(const float4*)(src);
        const float4 v1 = *(const float4*)(src + 4);
        short8 o;
        o[0] = (short)f2bf(v0.x); o[1] = (short)f2bf(v0.y);
        o[2] = (short)f2bf(v0.z); o[3] = (short)f2bf(v0.w);
        o[4] = (short)f2bf(v1.x); o[5] = (short)f2bf(v1.y);
        o[6] = (short)f2bf(v1.z); o[7] = (short)f2bf(v1.w);
        *(short8*)(gs + tid*8) = o;
    }
    __syncthreads();

    f32x4 acc[2][8];
    #pragma unroll
    for (int mt = 0; mt < 2; ++mt)
        #pragma unroll
        for (int nt = 0; nt < 8; ++nt) acc[mt][nt] = (f32x4){0.f,0.f,0.f,0.f};

    const ushort_t* basef = bt0f + (size_t)h*(32*32*512) + (size_t)(w4*8)*512 + (size_t)l*8;

    // emb K-steps: A uses W0 rows [0,256) (ks 0..7); C uses rows [256,512) (ks 8..15)
    {
        const int ksE0 = isC ? 8 : 0;
        for (int kk = 0; kk < 8; ++kk) {
            const int o = (lrow*512 + kk*64 + lko*16) ^ ((lrow & 7) << 4);
            const short8 a0 = *(const short8*)(es + o);
            const short8 a1 = *(const short8*)(es + o + 8192);
            const ushort_t* bp = basef + (size_t)(ksE0 + kk)*16384;
            #pragma unroll
            for (int nt = 0; nt < 8; ++nt) {
                const short8 bf = *(const short8*)(bp + nt*512);
                acc[0][nt] = __builtin_amdgcn_mfma_f32_16x16x32_bf16(a0, bf, acc[0][nt], 0, 0, 0);
                acc[1][nt] = __builtin_amdgcn_mfma_f32_16x16x32_bf16(a1, bf, acc[1][nt], 0, 0, 0);
            }
        }
    }
    // g K-steps (A only): W0 rows [512,1024) (ks 16..31); A-fragment is row-uniform
    if (!isC) {
        for (int kk = 0; kk < 16; ++kk) {
            const short8 ag = *(const short8*)(gs + kk*32 + lko*8);
            const ushort_t* bp = basef + (size_t)(16 + kk)*16384;
            #pragma unroll
            for (int nt = 0; nt < 8; ++nt) {
                const short8 bf = *(const short8*)(bp + nt*512);
                acc[0][nt] = __builtin_amdgcn_mfma_f32_16x16x32_bf16(ag, bf, acc[0][nt], 0, 0, 0);
                acc[1][nt] = __builtin_amdgcn_mfma_f32_16x16x32_bf16(ag, bf, acc[1][nt], 0, 0, 0);
            }
        }
    }

    ushort_t* dst = (isC ? Cbf : Abf) + (size_t)(h*64 + b)*32*512;
    #pragma unroll
    for (int nt = 0; nt < 8; ++nt) {
        const int col = (w4*8 + nt)*16 + lrow;
        const float g = isC ? 0.f : b0[h*512 + col];
        #pragma unroll
        for (int mt = 0; mt < 2; ++mt)
            #pragma unroll
            for (int r = 0; r < 4; ++r) {
                const int row = mt*16 + lko*4 + r;
                dst[row*512 + col] = f2bf(acc[mt][nt][r] + g);
            }
    }
}

// ================= K-MLP: M=64 row-tile fused MLP, 8 waves =================
// grid 1792: x<1024: h=3, b=x>>4, t0=(x&15)*2   (rows = 2t x 32s)
//            x>=1024: y=x-1024, h=y>>8, b=(y>>2)&63, t0=(y&3)*4 (rows = 4t x 16s window)
// 512 threads = 8 waves. Layer1: wave owns 2 nt; layer2: 1 nt; layer3: (nt=w&3, mhalf=w>>2).
__global__ __launch_bounds__(512, 2) void k_mlp(
    const ushort_t* __restrict__ Abf, const ushort_t* __restrict__ Cbf,
    const ushort_t* __restrict__ bt1, const ushort_t* __restrict__ bt2, const ushort_t* __restrict__ bt3,
    const float* __restrict__ b1, const float* __restrict__ b2, const float* __restrict__ b3,
    const float* __restrict__ w4, const float* __restrict__ b4,
    const int* __restrict__ np_, float* __restrict__ out, float* __restrict__ accbuf)
{
    const int x = blockIdx.x;
    const bool isH3 = (x < 1024);
    int h, b, t0;
    int n0 = 0, n1 = 0;
    if (isH3) {
        h = 3; b = x >> 4; t0 = (x & 15) * 2;
    } else {
        const int y = x - 1024;
        h = y >> 8; b = (y >> 2) & 63; t0 = (y & 3) * 4;
        n0 = np_[2*b]; n1 = np_[2*b+1];
        if (t0 >= n0) return;
    }

    __shared__ __align__(16) char smem[34816];
    char* X  = smem;                       // X0 half / X1 [64][256] bf16 (32KB); X2 [64][128] @0 (16KB)
    float* X3 = (float*)(smem + 16384);    // f32 [64][64] (16KB)
    float* X4 = (float*)(smem + 32768);    // f32 [64][4] (1KB)
    float* w4L = (float*)(smem + 33792);   // f32 [256] (1KB)

    const int tid = threadIdx.x;
    const int l = tid & 63, w = tid >> 6;
    const int lrow = l & 15, lko = l >> 4;
    const size_t hb = (size_t)(h*64 + b);
    const uint4* Arows = (const uint4*)(Abf + hb*32*512);   // 64 uint4 per row
    const uint4* Crows = (const uint4*)(Cbf + hb*32*512);

    float bias1v[2], bias2v, bias3v;
    #pragma unroll
    for (int nt = 0; nt < 2; ++nt) bias1v[nt] = b1[h*256 + (w*2 + nt)*16 + lrow];
    bias2v = b2[h*128 + w*16 + lrow];
    bias3v = b3[h*64 + (w & 3)*16 + lrow];
    if (tid < 256) w4L[tid] = w4[h*256 + tid];
    const int mhalf = w >> 2;

    // ---- layer1: two K=256 half-passes over one 32KB X0 buffer ----
    f32x4 acc1[4][2];
    #pragma unroll
    for (int mt = 0; mt < 4; ++mt)
        #pragma unroll
        for (int nt = 0; nt < 2; ++nt) acc1[mt][nt] = (f32x4){0.f,0.f,0.f,0.f};

    for (int p = 0; p < 2; ++p) {
        if (p) __syncthreads();   // previous pass readers done
        #pragma unroll
        for (int i = 0; i < 4; ++i) {
            const int flat = i*512 + tid;        // [64 rows][32 uint4]
            const int row = flat >> 5, q4 = flat & 31;
            int trow, crow;
            if (isH3) { trow = t0 + (row >> 5); crow = row & 31; }
            else      { trow = t0 + (row >> 4); crow = n0 + (row & 15); }
            const uint4 aa = Arows[(size_t)trow*64 + p*32 + q4];
            const uint4 cc = Crows[(size_t)crow*64 + p*32 + q4];
            uint4 v;
            v.x = bfadd2_relu(aa.x, cc.x);
            v.y = bfadd2_relu(aa.y, cc.y);
            v.z = bfadd2_relu(aa.z, cc.z);
            v.w = bfadd2_relu(aa.w, cc.w);
            *(uint4*)(X + ((row*512 + q4*16) ^ ((row & 7) << 4))) = v;
        }
        __syncthreads();

        const ushort_t* bp = bt1 + (size_t)((h*16 + p*8)*16 + w*2)*512 + (size_t)l*8;
        short8 bb[2][2];
        #pragma unroll
        for (int nt = 0; nt < 2; ++nt) bb[0][nt] = *(const short8*)(bp + (size_t)nt*512);
        #pragma unroll
        for (int ks = 0; ks < 8; ++ks) {
            if (ks < 7) {
                #pragma unroll
                for (int nt = 0; nt < 2; ++nt)
                    bb[(ks+1)&1][nt] = *(const short8*)(bp + (size_t)(ks+1)*8192 + (size_t)nt*512);
            }
            short8 a[4];
            #pragma unroll
            for (int mt = 0; mt < 4; ++mt)
                a[mt] = *(const short8*)(X + (((mt*16 + lrow)*512 + ks*64 + lko*16) ^ ((lrow & 7) << 4)));
            #pragma unroll
            for (int nt = 0; nt < 2; ++nt)
                #pragma unroll
                for (int mt = 0; mt < 4; ++mt)
                    acc1[mt][nt] = __builtin_amdgcn_mfma_f32_16x16x32_bf16(a[mt], bb[ks&1][nt], acc1[mt][nt], 0, 0, 0);
        }
    }
    __syncthreads();

    // X1 write (overlays X0): [64][256] bf16 stride 512B
    #pragma unroll
    for (int nt = 0; nt < 2; ++nt) {
        const int col = (w*2 + nt)*16 + lrow;
        #pragma unroll
        for (int mt = 0; mt < 4; ++mt)
            #pragma unroll
            for (int r = 0; r < 4; ++r) {
                const int row = mt*16 + lko*4 + r;
                *(ushort_t*)(X + ((row*512 + col*2) ^ ((row & 7) << 4))) =
                    f2bf(fmaxf(acc1[mt][nt][r] + bias1v[nt], 0.f));
            }
    }
    __syncthreads();

    // ---- layer2: K=256, N=128; wave owns nt = w ----
    f32x4 acc2[4];
    #pragma unroll
    for (int mt = 0; mt < 4; ++mt) acc2[mt] = (f32x4){0.f,0.f,0.f,0.f};
    {
        const ushort_t* bp = bt2 + (size_t)(h*64 + w)*512 + (size_t)l*8;
        short8 bb[2];
        bb[0] = *(const short8*)(bp);
        #pragma unroll
        for (int ks = 0; ks < 8; ++ks) {
            if (ks < 7) bb[(ks+1)&1] = *(const short8*)(bp + (size_t)(ks+1)*4096);
            short8 a[4];
            #pragma unroll
            for (int mt = 0; mt < 4; ++mt)
                a[mt] = *(const short8*)(X + (((mt*16 + lrow)*512 + ks*64 + lko*16) ^ ((lrow & 7) << 4)));
            #pragma unroll
            for (int mt = 0; mt < 4; ++mt)
                acc2[mt] = __builtin_amdgcn_mfma_f32_16x16x32_bf16(a[mt], bb[ks&1], acc2[mt], 0, 0, 0);
        }
    }
    __syncthreads();

    // X2 write (overlays X[0..16K)): [64][128] bf16 stride 256B
    {
        const int col = w*16 + lrow;
        #pragma unroll
        for (int mt = 0; mt < 4; ++mt)
            #pragma unroll
            for (int r = 0; r < 4; ++r) {
                const int row = mt*16 + lko*4 + r;
                *(ushort_t*)(X + ((row*256 + col*2) ^ ((row & 7) << 4))) =
                    f2bf(fmaxf(acc2[mt][r] + bias2v, 0.f));
            }
    }
    __syncthreads();

    // ---- layer3: K=128, N=64; wave = (nt=w&3, mhalf) ----
    f32x4 acc3[2];
    acc3[0] = (f32x4){0.f,0.f,0.f,0.f};
    acc3[1] = (f32x4){0.f,0.f,0.f,0.f};
    {
        const ushort_t* bp = bt3 + (size_t)(h*16 + (w & 3))*512 + (size_t)l*8;
        short8 F3[4];
        #pragma unroll
        for (int ks = 0; ks < 4; ++ks) F3[ks] = *(const short8*)(bp + (size_t)ks*2048);
        #pragma unroll
        for (int ks = 0; ks < 4; ++ks) {
            #pragma unroll
            for (int mi = 0; mi < 2; ++mi) {
                const int mt = mhalf*2 + mi;
                const short8 a0 = *(const short8*)(X + (((mt*16 + lrow)*256 + ks*64 + lko*16) ^ ((lrow & 7) << 4)));
                acc3[mi] = __builtin_amdgcn_mfma_f32_16x16x32_bf16(a0, F3[ks], acc3[mi], 0, 0, 0);
            }
        }
    }
    // X3 write @16-32K (X1 upper half, dead since X2-write barrier)
    {
        const int col = (w & 3)*16 + lrow;
        #pragma unroll
        for (int mi = 0; mi < 2; ++mi) {
            const int mt = mhalf*2 + mi;
            #pragma unroll
            for (int r = 0; r < 4; ++r)
                X3[(mt*16 + lko*4 + r)*64 + col] = fmaxf(acc3[mi][r] + bias3v, 0.f);
        }
    }
    __syncthreads();

    // ---- layer4: 64 -> 4 (VALU, 256 threads, bank-staggered) ----
    if (tid < 256) {
        const int row = tid >> 2, o = tid & 3;
        float a = b4[h*4 + o];
        #pragma unroll
        for (int dd = 0; dd < 16; ++dd) {
            const int dbase = ((row + dd) & 15) * 4;
            const float4 xv = *(const float4*)(X3 + row*64 + dbase);
            a = fmaf(xv.x, w4L[(dbase + 0)*4 + o], a);
            a = fmaf(xv.y, w4L[(dbase + 1)*4 + o], a);
            a = fmaf(xv.z, w4L[(dbase + 2)*4 + o], a);
            a = fmaf(xv.w, w4L[(dbase + 3)*4 + o], a);
        }
        X4[row*4 + o] = a;
    }
    __syncthreads();

    // ---- outputs ----
    if (isH3) {
        if (tid < 64) {
            const int tq = tid >> 5, s = tid & 31;
            out[O_PLANE + b*1024 + (t0 + tq)*32 + s] = 1.f / (1.f + expf(-X4[tid*4]));
        }
    } else {
        const int nj = (h == 0) ? 1 : ((h == 1) ? 4 : 3);
        const int j = w;
        if (j < nj) {
            const int tq = l >> 4, sr = l & 15;
            const bool valid = ((t0 + tq) < n0) && (sr < n1);
            float v = valid ? X4[l*4 + j] : 0.f;
            #pragma unroll
            for (int off = 32; off > 0; off >>= 1) v += __shfl_down(v, off);
            if (l == 0) {
                const int slot = (h == 0) ? 0 : ((h == 1) ? 1 + j : 5 + j);
                atomicAdd(&accbuf[b*8 + slot], v);
            }
        }
    }
}

// ================= K-final: finalize scalar reductions =================
__global__ __launch_bounds__(512) void k_final(
    const int* __restrict__ np_, const float* __restrict__ acc, float* __restrict__ out)
{
    const int tid = threadIdx.x;
    const int b = tid >> 3, sl = tid & 7;
    const int n0 = np_[2*b], n1 = np_[2*b+1];
    const float pf = (float)(n0 * n1);
    const float v = acc[b*8 + sl] / pf;
    if (sl == 0)      out[O_CAM + b] = 1.f / (1.f + expf(-v));
    else if (sl <= 4) out[O_ROT + b*4 + (sl - 1)] = v;
    else              out[O_TRANS + b*3 + (sl - 5)] = v;
}

extern "C" void kernel_launch(void* const* d_in, const int* in_sizes, int n_in,
                              void* d_out, int out_size, void* d_ws, size_t ws_size,
                              hipStream_t stream) {
    (void)in_sizes; (void)n_in; (void)out_size; (void)ws_size;
    const float* emb = (const float*)d_in[0];
    const int*   np_ = (const int*)d_in[1];
    const float* w0  = (const float*)d_in[2];
    const float* b0  = (const float*)d_in[3];
    const float* w1  = (const float*)d_in[4];
    const float* b1  = (const float*)d_in[5];
    const float* w2  = (const float*)d_in[6];
    const float* b2  = (const float*)d_in[7];
    const float* w3  = (const float*)d_in[8];
    const float* b3  = (const float*)d_in[9];
    const float* w4  = (const float*)d_in[10];
    const float* b4  = (const float*)d_in[11];

    char* W = (char*)d_ws;
    float* out = (float*)d_out;
    float*    g1   = (float*)(W + B_G1);
    float*    g2   = (float*)(W + B_G2);
    float*    acc  = (float*)(W + B_ACC);
    ushort_t* Abf  = (ushort_t*)(W + B_ABF);
    ushort_t* Cbf  = (ushort_t*)(W + B_CBF);
    ushort_t* bt1  = (ushort_t*)(W + B_BT1);
    ushort_t* bt2  = (ushort_t*)(W + B_BT2);
    ushort_t* bt3  = (ushort_t*)(W + B_BT3);
    ushort_t* bt0f = (ushort_t*)(W + B_BT0F);

    k_prep<<<5569, 64, 0, stream>>>(emb, np_, w0, w1, w2, w3,
                                    bt1, bt2, bt3, bt0f, g1, g2, acc, out);
    k_AC<<<dim3(64, 8), 256, 0, stream>>>(emb, bt0f, g1, g2, b0, Abf, Cbf);
    k_mlp<<<1792, 512, 0, stream>>>(Abf, Cbf, bt1, bt2, bt3,
                                    b1, b2, b3, w4, b4, np_, out, acc);
    k_final<<<1, 512, 0, stream>>>(np_, acc, out);
}